// Round 6
// baseline (259.650 us; speedup 1.0000x reference)
//
#include <hip/hip_runtime.h>
#include <math.h>

#define EPS 1e-5f
#define SLOPE 0.2f

typedef unsigned short u16;
typedef unsigned int u32;
typedef __attribute__((ext_vector_type(4))) float f32x4;
typedef __attribute__((ext_vector_type(8))) short s16x8;
typedef __attribute__((ext_vector_type(4))) short s16x4;

__device__ __forceinline__ float lrelu(float x){ return x >= 0.f ? x : SLOPE*x; }

// f32 -> bf16 bits, round-to-nearest-even
__device__ __forceinline__ u16 f2b(float x){
  u32 u = __float_as_uint(x);
  u32 r = (u + 0x7FFFu + ((u >> 16) & 1u)) >> 16;
  return (u16)r;
}
__device__ __forceinline__ float b2f(short v){
  return __uint_as_float(((u32)(u16)v) << 16);
}

// ---------- NCHW f32 [4,256,32,32] -> NHWC bf16 [4,1024,256] (LDS transpose)
__global__ void k_tr(const float* __restrict__ x, u16* __restrict__ xh){
  __shared__ float t[32][33];
  int b = blockIdx.x>>8; int c0 = ((blockIdx.x>>5)&7)*32; int p0 = (blockIdx.x&31)*32;
  int tx = threadIdx.x&31, ty = threadIdx.x>>5;   // 32 x 8
  #pragma unroll
  for(int r=0;r<32;r+=8)
    t[ty+r][tx] = x[((size_t)(b*256 + c0+ty+r))*1024 + p0 + tx];
  __syncthreads();
  #pragma unroll
  for(int r=0;r<32;r+=8)
    xh[((size_t)(b*1024 + p0+ty+r))*256 + c0 + tx] = f2b(t[tx][ty+r]);
}

// ---------- bilinear x2 upsample (align_corners) NHWC bf16
__global__ void k_up8(const u16* __restrict__ xh, u16* __restrict__ u){
  int idx = blockIdx.x*256 + threadIdx.x;    // 524288 total (8 ch per thread)
  int cg = idx & 31;
  int ow = (idx>>5) & 63; int oh = (idx>>11)&63; int b = idx>>17;
  const float st = 31.0f/63.0f;
  float fh = oh*st, fw = ow*st;
  int h0=(int)fh, w0=(int)fw;
  float wh = fh-(float)h0, ww = fw-(float)w0;
  int h1=min(h0+1,31), w1=min(w0+1,31);
  const u16* xb = xh + ((size_t)b*1024)*256 + cg*8;
  s16x8 a = *(const s16x8*)(xb + (size_t)(h0*32+w0)*256);
  s16x8 bb= *(const s16x8*)(xb + (size_t)(h0*32+w1)*256);
  s16x8 c = *(const s16x8*)(xb + (size_t)(h1*32+w0)*256);
  s16x8 d = *(const s16x8*)(xb + (size_t)(h1*32+w1)*256);
  u16 o[8];
  #pragma unroll
  for(int j=0;j<8;++j){
    float top = b2f(a[j]) + (b2f(bb[j])-b2f(a[j]))*ww;
    float bot = b2f(c[j]) + (b2f(d[j])-b2f(c[j]))*ww;
    o[j] = f2b(top + (bot-top)*wh);
  }
  *(s16x8*)(u + (size_t)idx*8) = *(s16x8*)o;
}

// ---------- conv weight transform: OIHW f32 -> [co][tap*Cin+ci] bf16
template<int CIN>
__global__ void k_wconv(const float* __restrict__ W, u16* __restrict__ wt){
  int idx = blockIdx.x*256 + threadIdx.x;
  int ci = idx & (CIN-1);
  int t2 = idx / CIN;
  int tap = t2 % 9;
  int co = t2 / 9;
  wt[idx] = f2b(W[((size_t)co*CIN + ci)*9 + tap]);
}

// ---------- projection weight transform
__global__ void k_wproj(const float* __restrict__ Wq, const float* __restrict__ Wk,
                        const float* __restrict__ Wv, u16* __restrict__ wqk,
                        u16* __restrict__ wv){
  int idx = blockIdx.x*256 + threadIdx.x;
  if(idx < 16384){
    float v_ = idx < 8192 ? Wq[idx] : Wk[idx-8192];
    wqk[idx] = f2b(v_);
  } else {
    wv[idx-16384] = f2b(Wv[idx-16384]);
  }
}

// ---------- implicit-GEMM 3x3 conv (MFMA) + BN + LReLU, NHWC bf16
// wave: 32 px x 64 co; block 2 waves (64 px x 64 co); grid 64mt x 2nt x 4b = 512
template<int CIN>
__global__ __launch_bounds__(128) void k_cmfma(
    const u16* __restrict__ xin, const u16* __restrict__ wt,
    const float* __restrict__ bias,
    const float* __restrict__ g, const float* __restrict__ be,
    const float* __restrict__ mm, const float* __restrict__ vv,
    u16* __restrict__ out)
{
  constexpr int K = CIN*9;
  int blk = blockIdx.x;
  int mt = blk & 63;
  int nt = (blk>>6) & 1;
  int b  = blk >> 7;
  int wid = threadIdx.x>>6, lane = threadIdx.x&63;
  int gq = lane>>4, lr = lane&15;
  int g8 = gq*8;
  int mb = mt*64 + wid*32;
  int h = mb>>6, w0 = mb&63;
  int cob = nt*64;

  f32x4 acc[2][4];
  #pragma unroll
  for(int pf=0;pf<2;++pf)
    #pragma unroll
    for(int cf=0;cf<4;++cf) acc[pf][cf]=(f32x4)0.f;

  const u16* xb = xin + (size_t)b*4096*CIN;
  const u16* wr = wt + (size_t)(cob+lr)*K + g8;

  for(int dy=-1; dy<=1; ++dy){
    int hh = h+dy;
    if(hh<0 || hh>63) continue;
    #pragma unroll
    for(int dx=-1; dx<=1; ++dx){
      int tap = (dy+1)*3 + (dx+1);
      const u16* wtap = wr + tap*CIN;
      const u16* ar[2]; bool av[2];
      #pragma unroll
      for(int pf=0;pf<2;++pf){
        int ww = w0 + pf*16 + lr + dx;
        av[pf] = (ww>=0)&&(ww<64);
        int wc = ww<0?0:(ww>63?63:ww);
        ar[pf] = xb + ((size_t)hh*64 + wc)*CIN + g8;
      }
      #pragma unroll
      for(int kc=0;kc<CIN/32;++kc){
        s16x8 af[2];
        #pragma unroll
        for(int pf=0;pf<2;++pf){
          s16x8 t = *(const s16x8*)(ar[pf] + kc*32);
          af[pf] = av[pf] ? t : (s16x8)0;
        }
        s16x8 bfr[4];
        #pragma unroll
        for(int cf=0;cf<4;++cf)
          bfr[cf] = *(const s16x8*)(wtap + (size_t)cf*16*K + kc*32);
        #pragma unroll
        for(int pf=0;pf<2;++pf)
          #pragma unroll
          for(int cf=0;cf<4;++cf)
            acc[pf][cf] = __builtin_amdgcn_mfma_f32_16x16x32_bf16(af[pf], bfr[cf], acc[pf][cf],0,0,0);
      }
    }
  }
  #pragma unroll
  for(int cf=0;cf<4;++cf){
    int co = cob + cf*16 + lr;
    float sc = g[co]*rsqrtf(vv[co]+EPS);
    float sh = be[co] - mm[co]*sc;
    if(bias) sh += bias[co]*sc;
    #pragma unroll
    for(int pf=0;pf<2;++pf){
      #pragma unroll
      for(int r=0;r<4;++r){
        int pix = mb + pf*16 + gq*4 + r;
        float v_ = acc[pf][cf][r]*sc + sh;
        out[((size_t)b*4096 + pix)*128 + co] = f2b(lrelu(v_));
      }
    }
  }
}

// ---------- fused q,k projection
__global__ __launch_bounds__(128) void k_projqk(
  const u16* __restrict__ x2b, const u16* __restrict__ wqk,
  const float* __restrict__ bq, const float* __restrict__ bk,
  u16* __restrict__ qbf, u16* __restrict__ kbf)
{
  int blk = blockIdx.x;           // 512 = 256 mt x 2 nt
  int nt = blk & 1;
  int mt = blk >> 1;
  int wid = threadIdx.x>>6, lane = threadIdx.x&63;
  int gq=lane>>4, lr=lane&15, g8=gq*8;
  int mb = mt*64 + wid*32;
  int cob = nt*64;
  f32x4 acc[2][4];
  #pragma unroll
  for(int pf=0;pf<2;++pf)
    #pragma unroll
    for(int cf=0;cf<4;++cf) acc[pf][cf]=(f32x4)0.f;
  const u16* xr0 = x2b + (size_t)(mb+lr)*128 + g8;
  const u16* xr1 = x2b + (size_t)(mb+16+lr)*128 + g8;
  const u16* wr  = wqk + (size_t)(cob+lr)*128 + g8;
  #pragma unroll
  for(int kc=0;kc<4;++kc){
    s16x8 a0 = *(const s16x8*)(xr0 + kc*32);
    s16x8 a1 = *(const s16x8*)(xr1 + kc*32);
    s16x8 bfr[4];
    #pragma unroll
    for(int cf=0;cf<4;++cf) bfr[cf] = *(const s16x8*)(wr + (size_t)cf*16*128 + kc*32);
    #pragma unroll
    for(int cf=0;cf<4;++cf){
      acc[0][cf] = __builtin_amdgcn_mfma_f32_16x16x32_bf16(a0, bfr[cf], acc[0][cf],0,0,0);
      acc[1][cf] = __builtin_amdgcn_mfma_f32_16x16x32_bf16(a1, bfr[cf], acc[1][cf],0,0,0);
    }
  }
  #pragma unroll
  for(int cf=0;cf<4;++cf){
    int co = cob + cf*16 + lr;
    float bi = co<64 ? bq[co] : bk[co-64];
    #pragma unroll
    for(int pf=0;pf<2;++pf){
      #pragma unroll
      for(int r=0;r<4;++r){
        int pix = mb + pf*16 + gq*4 + r;
        float v_ = acc[pf][cf][r] + bi;
        if(co<64) qbf[(size_t)pix*64 + co] = f2b(v_);
        else      kbf[(size_t)pix*64 + (co-64)] = f2b(v_);
      }
    }
  }
}

// ---------- v projection, transposed output: vbf[b][co][pix]
__global__ __launch_bounds__(128) void k_projv(
  const u16* __restrict__ x2b, const u16* __restrict__ wv,
  const float* __restrict__ bv, u16* __restrict__ vbf)
{
  int blk = blockIdx.x;      // 512 = 4 cot x 32 pt x 4 b
  int cot = blk & 3;
  int pt  = (blk>>2) & 31;
  int b   = blk >> 7;
  int wid = threadIdx.x>>6, lane = threadIdx.x&63;
  int gq=lane>>4, lr=lane&15, g8=gq*8;
  int cb = cot*32;
  int nb = pt*128 + wid*64;
  f32x4 acc[2][4];
  #pragma unroll
  for(int pf=0;pf<2;++pf)
    #pragma unroll
    for(int cf=0;cf<4;++cf) acc[pf][cf]=(f32x4)0.f;
  const u16* ar0 = wv + (size_t)(cb+lr)*128 + g8;
  const u16* ar1 = wv + (size_t)(cb+16+lr)*128 + g8;
  const u16* xr  = x2b + ((size_t)b*4096 + nb + lr)*128 + g8;
  #pragma unroll
  for(int kc=0;kc<4;++kc){
    s16x8 a0 = *(const s16x8*)(ar0+kc*32);
    s16x8 a1 = *(const s16x8*)(ar1+kc*32);
    s16x8 bfr[4];
    #pragma unroll
    for(int cf=0;cf<4;++cf) bfr[cf] = *(const s16x8*)(xr + (size_t)cf*16*128 + kc*32);
    #pragma unroll
    for(int cf=0;cf<4;++cf){
      acc[0][cf] = __builtin_amdgcn_mfma_f32_16x16x32_bf16(a0, bfr[cf], acc[0][cf],0,0,0);
      acc[1][cf] = __builtin_amdgcn_mfma_f32_16x16x32_bf16(a1, bfr[cf], acc[1][cf],0,0,0);
    }
  }
  #pragma unroll
  for(int pf=0;pf<2;++pf){
    #pragma unroll
    for(int r=0;r<4;++r){
      int co = cb + pf*16 + gq*4 + r;
      float bi = bv[co];
      #pragma unroll
      for(int cf=0;cf<4;++cf){
        int pix = nb + cf*16 + lr;
        vbf[((size_t)b*128+co)*4096 + pix] = f2b(acc[pf][cf][r] + bi);
      }
    }
  }
}

// ---------- MFMA flash attention, KV-split x8, 32 q-rows/wave, 8 waves/block
// grid 512 blocks (b from blk&7 -> XCD-local KV); two-phase 64KB LDS combine
__global__ __launch_bounds__(512, 4) void k_fattn2(
    const u16* __restrict__ qbf, const u16* __restrict__ kbf,
    const u16* __restrict__ vbf, const u16* __restrict__ x2b,
    const u16* __restrict__ idbb, float* __restrict__ out){
  __shared__ float smem[16384 + 512];   // 64KB dump (aliases P bounce) + stats
  float* sst = smem + 16384;            // [w][pf][lr][2]
  int wid = threadIdx.x>>6, lane = threadIdx.x&63;
  int gq = lane>>4, lr = lane&15;
  int blk = blockIdx.x;
  int b  = (blk&7)>>1;
  int mt = ((blk>>3)<<1) | (blk&1);     // 0..127
  int mbase = mt*32;

  // Q B-fragments, 2 m-frags (rows mbase+lr, mbase+16+lr)
  const u16* qp = qbf + ((size_t)b*4096 + mbase + lr)*64 + gq*8;
  s16x8 qf[2][2];
  qf[0][0] = *(const s16x8*)qp;
  qf[0][1] = *(const s16x8*)(qp + 32);
  qf[1][0] = *(const s16x8*)(qp + 16*64);
  qf[1][1] = *(const s16x8*)(qp + 16*64 + 32);

  f32x4 acc[2][8];
  #pragma unroll
  for(int pf=0;pf<2;++pf)
    #pragma unroll
    for(int i=0;i<8;++i) acc[pf][i] = (f32x4)0.f;
  float mrun[2] = {-3.0e38f, -3.0e38f}, lrun[2] = {0.f, 0.f};

  const u16* kb0 = kbf + (size_t)b*4096*64 + (size_t)lr*64 + gq*8;
  const u16* vb0 = vbf + ((size_t)b*128 + lr)*4096 + gq*8;

  // wave-private P bounce: 4KB per wave (floats offset wid*1024)
  u16* pw = (u16*)(smem + wid*1024);
  u32 swz = ((u32)(lr & 7)) << 4;
  u32 wb[4];
  #pragma unroll
  for(int nf=0;nf<4;++nf) wb[nf] = ((u32)((lr*64 + nf*16 + gq*4)*2)) ^ swz;
  u32 rb0 = ((u32)((lr*64 + gq*8)*2)) ^ swz;
  u32 rb1 = ((u32)((lr*64 + 32 + gq*8)*2)) ^ swz;

  for(int t=0; t<8; ++t){
    int nt = wid*8 + t;
    const u16* kp = kb0 + (size_t)nt*64*64;
    f32x4 sf[2][4];
    __builtin_amdgcn_s_setprio(1);
    #pragma unroll
    for(int nf=0;nf<4;++nf){
      s16x8 ka0 = *(const s16x8*)(kp + nf*16*64);
      s16x8 ka1 = *(const s16x8*)(kp + nf*16*64 + 32);
      #pragma unroll
      for(int pf=0;pf<2;++pf){
        f32x4 z = (f32x4)0.f;
        z = __builtin_amdgcn_mfma_f32_16x16x32_bf16(ka0, qf[pf][0], z, 0, 0, 0);
        z = __builtin_amdgcn_mfma_f32_16x16x32_bf16(ka1, qf[pf][1], z, 0, 0, 0);
        sf[pf][nf] = z;
      }
    }
    __builtin_amdgcn_s_setprio(0);
    #pragma unroll
    for(int pf=0;pf<2;++pf){
      float tm = -3.0e38f;
      #pragma unroll
      for(int nf=0;nf<4;++nf)
        #pragma unroll
        for(int r=0;r<4;++r) tm = fmaxf(tm, sf[pf][nf][r]);
      tm = fmaxf(tm, __shfl_xor(tm, 16));
      tm = fmaxf(tm, __shfl_xor(tm, 32));
      float mnew = fmaxf(mrun[pf], tm);
      float alpha = __expf(mrun[pf] - mnew);
      float ps = 0.f;
      #pragma unroll
      for(int nf=0;nf<4;++nf)
        #pragma unroll
        for(int r=0;r<4;++r){ float p = __expf(sf[pf][nf][r] - mnew); sf[pf][nf][r] = p; ps += p; }
      ps += __shfl_xor(ps, 16);
      ps += __shfl_xor(ps, 32);
      lrun[pf] = lrun[pf]*alpha + ps;
      mrun[pf] = mnew;
      #pragma unroll
      for(int i=0;i<8;++i) acc[pf][i] *= alpha;
      #pragma unroll
      for(int nf=0;nf<4;++nf){
        u32 lo = (u32)f2b(sf[pf][nf][0]) | ((u32)f2b(sf[pf][nf][1]) << 16);
        u32 hi = (u32)f2b(sf[pf][nf][2]) | ((u32)f2b(sf[pf][nf][3]) << 16);
        uint2 wv; wv.x = lo; wv.y = hi;
        *(uint2*)((char*)pw + (pf*2048 + wb[nf])) = wv;
      }
    }
    s16x8 pb[2][2];
    #pragma unroll
    for(int pf=0;pf<2;++pf){
      pb[pf][0] = *(const s16x8*)((char*)pw + (pf*2048 + rb0));
      pb[pf][1] = *(const s16x8*)((char*)pw + (pf*2048 + rb1));
    }
    const u16* vp = vb0 + nt*64;
    __builtin_amdgcn_s_setprio(1);
    #pragma unroll
    for(int cf=0;cf<8;++cf){
      s16x8 va0 = *(const s16x8*)(vp + (size_t)cf*16*4096);
      s16x8 va1 = *(const s16x8*)(vp + (size_t)cf*16*4096 + 32);
      #pragma unroll
      for(int pf=0;pf<2;++pf){
        acc[pf][cf] = __builtin_amdgcn_mfma_f32_16x16x32_bf16(va0, pb[pf][0], acc[pf][cf], 0, 0, 0);
        acc[pf][cf] = __builtin_amdgcn_mfma_f32_16x16x32_bf16(va1, pb[pf][1], acc[pf][cf], 0, 0, 0);
      }
    }
    __builtin_amdgcn_s_setprio(0);
  }

  // stats dump: [wid][pf][lr] -> max index ((7*2+1)*16+15)*2+1 = 511
  if(gq == 0){
    #pragma unroll
    for(int pf=0;pf<2;++pf){
      sst[((wid*2+pf)*16 + lr)*2 + 0] = mrun[pf];
      sst[((wid*2+pf)*16 + lr)*2 + 1] = lrun[pf];
    }
  }

  // two-phase combine: per pf, dump 64KB (8 waves x 8KB) then merge (cf = wid)
  #pragma unroll
  for(int pf=0;pf<2;++pf){
    __syncthreads();   // P-bounce use / previous-phase reads complete; stats visible
    #pragma unroll
    for(int cf=0;cf<8;++cf)
      *(f32x4*)(smem + wid*2048 + cf*256 + lane*4) = acc[pf][cf];
    __syncthreads();
    float mw[8], lw[8], Mx = -3.0e38f;
    #pragma unroll
    for(int w=0;w<8;++w){
      mw[w] = sst[((w*2+pf)*16 + lr)*2 + 0];
      lw[w] = sst[((w*2+pf)*16 + lr)*2 + 1];
      Mx = fmaxf(Mx, mw[w]);
    }
    float sw[8], lstar = 0.f;
    #pragma unroll
    for(int w=0;w<8;++w){ sw[w] = __expf(mw[w] - Mx); lstar += lw[w]*sw[w]; }
    float inv = 1.f/lstar;
    int m = mbase + pf*16 + lr;
    int cf = wid;
    f32x4 O = (f32x4)0.f;
    #pragma unroll
    for(int w=0;w<8;++w)
      O += sw[w] * *(const f32x4*)(smem + w*2048 + cf*256 + lane*4);
    int c0 = cf*16 + gq*4;
    size_t rbase = ((size_t)b*4096 + m)*128 + c0;
    s16x4 xr = *(const s16x4*)(x2b + rbase);
    s16x4 ir = *(const s16x4*)(idbb + rbase);
    #pragma unroll
    for(int r=0;r<4;++r){
      float val = O[r]*inv + b2f(xr[r]) + b2f(ir[r]);
      out[((size_t)b*128 + c0 + r)*4096 + m] = lrelu(val);
    }
  }
}

extern "C" void kernel_launch(void* const* d_in, const int* in_sizes, int n_in,
                              void* d_out, int out_size, void* d_ws, size_t ws_size,
                              hipStream_t stream) {
  const float* x    = (const float*)d_in[0];
  const float* W_up = (const float*)d_in[1];
  const float* b_up = (const float*)d_in[2];
  const float* g0   = (const float*)d_in[3];
  const float* be0  = (const float*)d_in[4];
  const float* m0   = (const float*)d_in[5];
  const float* v0   = (const float*)d_in[6];
  const float* W_r0 = (const float*)d_in[7];
  const float* g1   = (const float*)d_in[8];
  const float* be1  = (const float*)d_in[9];
  const float* m1   = (const float*)d_in[10];
  const float* v1   = (const float*)d_in[11];
  const float* W_r1 = (const float*)d_in[12];
  const float* g2   = (const float*)d_in[13];
  const float* be2  = (const float*)d_in[14];
  const float* m2   = (const float*)d_in[15];
  const float* v2   = (const float*)d_in[16];
  const float* Wq   = (const float*)d_in[17];
  const float* bq   = (const float*)d_in[18];
  const float* Wk   = (const float*)d_in[19];
  const float* bk   = (const float*)d_in[20];
  const float* Wv   = (const float*)d_in[21];
  const float* bv   = (const float*)d_in[22];

  float* ws = (float*)d_ws;
  u16* xh   = (u16*)(ws + 0);         // [4,1024,256]
  u16* ub   = (u16*)(ws + 524288);    // [4,4096,256]
  u16* idbb = (u16*)(ws + 2621440);   // [4,4096,128]
  u16* x1b  = (u16*)(ws + 3670016);   // [4,4096,128]
  u16* x2b  = (u16*)(ws + 4718592);   // [4,4096,128]
  u16* qbf  = (u16*)(ws + 5767168);   // [4,4096,64]
  u16* kbf  = (u16*)(ws + 6291456);   // [4,4096,64]
  u16* vbf  = (u16*)(ws + 6815744);   // [4,128,4096]
  u16* wtu  = (u16*)(ws + 7864320);   // [128,2304]
  u16* wtr0 = (u16*)(ws + 8011776);   // [128,1152]
  u16* wtr1 = (u16*)(ws + 8085504);   // [128,1152]
  u16* wqk  = (u16*)(ws + 8159232);   // [128,128]
  u16* wvb  = (u16*)(ws + 8167424);   // [128,128]
  float* out = (float*)d_out;

  // weight transforms
  k_wconv<256><<<1152, 256, 0, stream>>>(W_up, wtu);
  k_wconv<128><<<576, 256, 0, stream>>>(W_r0, wtr0);
  k_wconv<128><<<576, 256, 0, stream>>>(W_r1, wtr1);
  k_wproj<<<128, 256, 0, stream>>>(Wq, Wk, Wv, wqk, wvb);
  // input layout + upsample
  k_tr<<<1024, 256, 0, stream>>>(x, xh);
  k_up8<<<2048, 256, 0, stream>>>(xh, ub);
  // convs (MFMA implicit GEMM, round-4 config)
  k_cmfma<256><<<512, 128, 0, stream>>>(ub, wtu, b_up, g0, be0, m0, v0, idbb);
  k_cmfma<128><<<512, 128, 0, stream>>>(idbb, wtr0, nullptr, g1, be1, m1, v1, x1b);
  k_cmfma<128><<<512, 128, 0, stream>>>(x1b, wtr1, nullptr, g2, be2, m2, v2, x2b);
  // projections
  k_projqk<<<512, 128, 0, stream>>>(x2b, wqk, bq, bk, qbf, kbf);
  k_projv<<<512, 128, 0, stream>>>(x2b, wvb, bv, vbf);
  // attention + residuals + lrelu (KV-split x8, 8 waves/block)
  k_fattn2<<<512, 512, 0, stream>>>(qbf, kbf, vbf, x2b, idbb, out);
}

// Round 7
// 234.163 us; speedup vs baseline: 1.1088x; 1.1088x over previous
//
#include <hip/hip_runtime.h>
#include <math.h>

#define EPS 1e-5f
#define SLOPE 0.2f

typedef unsigned short u16;
typedef unsigned int u32;
typedef __attribute__((ext_vector_type(4))) float f32x4;
typedef __attribute__((ext_vector_type(8))) short s16x8;
typedef __attribute__((ext_vector_type(4))) short s16x4;

__device__ __forceinline__ float lrelu(float x){ return x >= 0.f ? x : SLOPE*x; }

// f32 -> bf16 bits, round-to-nearest-even
__device__ __forceinline__ u16 f2b(float x){
  u32 u = __float_as_uint(x);
  u32 r = (u + 0x7FFFu + ((u >> 16) & 1u)) >> 16;
  return (u16)r;
}
__device__ __forceinline__ float b2f(short v){
  return __uint_as_float(((u32)(u16)v) << 16);
}

// ---------- NCHW f32 [4,256,32,32] -> NHWC bf16 [4,1024,256] (LDS transpose)
__global__ void k_tr(const float* __restrict__ x, u16* __restrict__ xh){
  __shared__ float t[32][33];
  int b = blockIdx.x>>8; int c0 = ((blockIdx.x>>5)&7)*32; int p0 = (blockIdx.x&31)*32;
  int tx = threadIdx.x&31, ty = threadIdx.x>>5;   // 32 x 8
  #pragma unroll
  for(int r=0;r<32;r+=8)
    t[ty+r][tx] = x[((size_t)(b*256 + c0+ty+r))*1024 + p0 + tx];
  __syncthreads();
  #pragma unroll
  for(int r=0;r<32;r+=8)
    xh[((size_t)(b*1024 + p0+ty+r))*256 + c0 + tx] = f2b(t[tx][ty+r]);
}

// ---------- bilinear x2 upsample (align_corners) NHWC bf16
__global__ void k_up8(const u16* __restrict__ xh, u16* __restrict__ u){
  int idx = blockIdx.x*256 + threadIdx.x;    // 524288 total (8 ch per thread)
  int cg = idx & 31;
  int ow = (idx>>5) & 63; int oh = (idx>>11)&63; int b = idx>>17;
  const float st = 31.0f/63.0f;
  float fh = oh*st, fw = ow*st;
  int h0=(int)fh, w0=(int)fw;
  float wh = fh-(float)h0, ww = fw-(float)w0;
  int h1=min(h0+1,31), w1=min(w0+1,31);
  const u16* xb = xh + ((size_t)b*1024)*256 + cg*8;
  s16x8 a = *(const s16x8*)(xb + (size_t)(h0*32+w0)*256);
  s16x8 bb= *(const s16x8*)(xb + (size_t)(h0*32+w1)*256);
  s16x8 c = *(const s16x8*)(xb + (size_t)(h1*32+w0)*256);
  s16x8 d = *(const s16x8*)(xb + (size_t)(h1*32+w1)*256);
  u16 o[8];
  #pragma unroll
  for(int j=0;j<8;++j){
    float top = b2f(a[j]) + (b2f(bb[j])-b2f(a[j]))*ww;
    float bot = b2f(c[j]) + (b2f(d[j])-b2f(c[j]))*ww;
    o[j] = f2b(top + (bot-top)*wh);
  }
  *(s16x8*)(u + (size_t)idx*8) = *(s16x8*)o;
}

// ---------- conv weight transform: OIHW f32 -> [co][tap*Cin+ci] bf16
template<int CIN>
__global__ void k_wconv(const float* __restrict__ W, u16* __restrict__ wt){
  int idx = blockIdx.x*256 + threadIdx.x;
  int ci = idx & (CIN-1);
  int t2 = idx / CIN;
  int tap = t2 % 9;
  int co = t2 / 9;
  wt[idx] = f2b(W[((size_t)co*CIN + ci)*9 + tap]);
}

// ---------- projection weight transform
__global__ void k_wproj(const float* __restrict__ Wq, const float* __restrict__ Wk,
                        const float* __restrict__ Wv, u16* __restrict__ wqk,
                        u16* __restrict__ wv){
  int idx = blockIdx.x*256 + threadIdx.x;
  if(idx < 16384){
    float v_ = idx < 8192 ? Wq[idx] : Wk[idx-8192];
    wqk[idx] = f2b(v_);
  } else {
    wv[idx-16384] = f2b(Wv[idx-16384]);
  }
}

// ---------- implicit-GEMM 3x3 conv (MFMA) + BN + LReLU, NHWC bf16
// wave: 32 px x 64 co; block 2 waves (64 px x 64 co); grid 64mt x 2nt x 4b = 512
template<int CIN>
__global__ __launch_bounds__(128) void k_cmfma(
    const u16* __restrict__ xin, const u16* __restrict__ wt,
    const float* __restrict__ bias,
    const float* __restrict__ g, const float* __restrict__ be,
    const float* __restrict__ mm, const float* __restrict__ vv,
    u16* __restrict__ out)
{
  constexpr int K = CIN*9;
  int blk = blockIdx.x;
  int mt = blk & 63;
  int nt = (blk>>6) & 1;
  int b  = blk >> 7;
  int wid = threadIdx.x>>6, lane = threadIdx.x&63;
  int gq = lane>>4, lr = lane&15;
  int g8 = gq*8;
  int mb = mt*64 + wid*32;
  int h = mb>>6, w0 = mb&63;
  int cob = nt*64;

  f32x4 acc[2][4];
  #pragma unroll
  for(int pf=0;pf<2;++pf)
    #pragma unroll
    for(int cf=0;cf<4;++cf) acc[pf][cf]=(f32x4)0.f;

  const u16* xb = xin + (size_t)b*4096*CIN;
  const u16* wr = wt + (size_t)(cob+lr)*K + g8;

  for(int dy=-1; dy<=1; ++dy){
    int hh = h+dy;
    if(hh<0 || hh>63) continue;
    #pragma unroll
    for(int dx=-1; dx<=1; ++dx){
      int tap = (dy+1)*3 + (dx+1);
      const u16* wtap = wr + tap*CIN;
      const u16* ar[2]; bool av[2];
      #pragma unroll
      for(int pf=0;pf<2;++pf){
        int ww = w0 + pf*16 + lr + dx;
        av[pf] = (ww>=0)&&(ww<64);
        int wc = ww<0?0:(ww>63?63:ww);
        ar[pf] = xb + ((size_t)hh*64 + wc)*CIN + g8;
      }
      #pragma unroll
      for(int kc=0;kc<CIN/32;++kc){
        s16x8 af[2];
        #pragma unroll
        for(int pf=0;pf<2;++pf){
          s16x8 t = *(const s16x8*)(ar[pf] + kc*32);
          af[pf] = av[pf] ? t : (s16x8)0;
        }
        s16x8 bfr[4];
        #pragma unroll
        for(int cf=0;cf<4;++cf)
          bfr[cf] = *(const s16x8*)(wtap + (size_t)cf*16*K + kc*32);
        #pragma unroll
        for(int pf=0;pf<2;++pf)
          #pragma unroll
          for(int cf=0;cf<4;++cf)
            acc[pf][cf] = __builtin_amdgcn_mfma_f32_16x16x32_bf16(af[pf], bfr[cf], acc[pf][cf],0,0,0);
      }
    }
  }
  #pragma unroll
  for(int cf=0;cf<4;++cf){
    int co = cob + cf*16 + lr;
    float sc = g[co]*rsqrtf(vv[co]+EPS);
    float sh = be[co] - mm[co]*sc;
    if(bias) sh += bias[co]*sc;
    #pragma unroll
    for(int pf=0;pf<2;++pf){
      #pragma unroll
      for(int r=0;r<4;++r){
        int pix = mb + pf*16 + gq*4 + r;
        float v_ = acc[pf][cf][r]*sc + sh;
        out[((size_t)b*4096 + pix)*128 + co] = f2b(lrelu(v_));
      }
    }
  }
}

// ---------- fused q,k projection
__global__ __launch_bounds__(128) void k_projqk(
  const u16* __restrict__ x2b, const u16* __restrict__ wqk,
  const float* __restrict__ bq, const float* __restrict__ bk,
  u16* __restrict__ qbf, u16* __restrict__ kbf)
{
  int blk = blockIdx.x;           // 512 = 256 mt x 2 nt
  int nt = blk & 1;
  int mt = blk >> 1;
  int wid = threadIdx.x>>6, lane = threadIdx.x&63;
  int gq=lane>>4, lr=lane&15, g8=gq*8;
  int mb = mt*64 + wid*32;
  int cob = nt*64;
  f32x4 acc[2][4];
  #pragma unroll
  for(int pf=0;pf<2;++pf)
    #pragma unroll
    for(int cf=0;cf<4;++cf) acc[pf][cf]=(f32x4)0.f;
  const u16* xr0 = x2b + (size_t)(mb+lr)*128 + g8;
  const u16* xr1 = x2b + (size_t)(mb+16+lr)*128 + g8;
  const u16* wr  = wqk + (size_t)(cob+lr)*128 + g8;
  #pragma unroll
  for(int kc=0;kc<4;++kc){
    s16x8 a0 = *(const s16x8*)(xr0 + kc*32);
    s16x8 a1 = *(const s16x8*)(xr1 + kc*32);
    s16x8 bfr[4];
    #pragma unroll
    for(int cf=0;cf<4;++cf) bfr[cf] = *(const s16x8*)(wr + (size_t)cf*16*128 + kc*32);
    #pragma unroll
    for(int cf=0;cf<4;++cf){
      acc[0][cf] = __builtin_amdgcn_mfma_f32_16x16x32_bf16(a0, bfr[cf], acc[0][cf],0,0,0);
      acc[1][cf] = __builtin_amdgcn_mfma_f32_16x16x32_bf16(a1, bfr[cf], acc[1][cf],0,0,0);
    }
  }
  #pragma unroll
  for(int cf=0;cf<4;++cf){
    int co = cob + cf*16 + lr;
    float bi = co<64 ? bq[co] : bk[co-64];
    #pragma unroll
    for(int pf=0;pf<2;++pf){
      #pragma unroll
      for(int r=0;r<4;++r){
        int pix = mb + pf*16 + gq*4 + r;
        float v_ = acc[pf][cf][r] + bi;
        if(co<64) qbf[(size_t)pix*64 + co] = f2b(v_);
        else      kbf[(size_t)pix*64 + (co-64)] = f2b(v_);
      }
    }
  }
}

// ---------- v projection, transposed output: vbf[b][co][pix]
__global__ __launch_bounds__(128) void k_projv(
  const u16* __restrict__ x2b, const u16* __restrict__ wv,
  const float* __restrict__ bv, u16* __restrict__ vbf)
{
  int blk = blockIdx.x;      // 512 = 4 cot x 32 pt x 4 b
  int cot = blk & 3;
  int pt  = (blk>>2) & 31;
  int b   = blk >> 7;
  int wid = threadIdx.x>>6, lane = threadIdx.x&63;
  int gq=lane>>4, lr=lane&15, g8=gq*8;
  int cb = cot*32;
  int nb = pt*128 + wid*64;
  f32x4 acc[2][4];
  #pragma unroll
  for(int pf=0;pf<2;++pf)
    #pragma unroll
    for(int cf=0;cf<4;++cf) acc[pf][cf]=(f32x4)0.f;
  const u16* ar0 = wv + (size_t)(cb+lr)*128 + g8;
  const u16* ar1 = wv + (size_t)(cb+16+lr)*128 + g8;
  const u16* xr  = x2b + ((size_t)b*4096 + nb + lr)*128 + g8;
  #pragma unroll
  for(int kc=0;kc<4;++kc){
    s16x8 a0 = *(const s16x8*)(ar0+kc*32);
    s16x8 a1 = *(const s16x8*)(ar1+kc*32);
    s16x8 bfr[4];
    #pragma unroll
    for(int cf=0;cf<4;++cf) bfr[cf] = *(const s16x8*)(xr + (size_t)cf*16*128 + kc*32);
    #pragma unroll
    for(int cf=0;cf<4;++cf){
      acc[0][cf] = __builtin_amdgcn_mfma_f32_16x16x32_bf16(a0, bfr[cf], acc[0][cf],0,0,0);
      acc[1][cf] = __builtin_amdgcn_mfma_f32_16x16x32_bf16(a1, bfr[cf], acc[1][cf],0,0,0);
    }
  }
  #pragma unroll
  for(int pf=0;pf<2;++pf){
    #pragma unroll
    for(int r=0;r<4;++r){
      int co = cb + pf*16 + gq*4 + r;
      float bi = bv[co];
      #pragma unroll
      for(int cf=0;cf<4;++cf){
        int pix = nb + cf*16 + lr;
        vbf[((size_t)b*128+co)*4096 + pix] = f2b(acc[pf][cf][r] + bi);
      }
    }
  }
}

// ---------- MFMA flash attention, KV-split x8, 32 q-rows/wave, 8 waves/block
// grid 512 blocks (b from blk&7 -> XCD-local KV); two-phase 64KB LDS combine
__global__ __launch_bounds__(512, 2) void k_fattn2(
    const u16* __restrict__ qbf, const u16* __restrict__ kbf,
    const u16* __restrict__ vbf, const u16* __restrict__ x2b,
    const u16* __restrict__ idbb, float* __restrict__ out){
  __shared__ float smem[16384 + 512];   // 64KB dump (aliases P bounce) + stats
  float* sst = smem + 16384;            // [w][pf][lr][2]
  int wid = threadIdx.x>>6, lane = threadIdx.x&63;
  int gq = lane>>4, lr = lane&15;
  int blk = blockIdx.x;
  int b  = (blk&7)>>1;
  int mt = ((blk>>3)<<1) | (blk&1);     // 0..127
  int mbase = mt*32;

  // Q B-fragments, 2 m-frags (rows mbase+lr, mbase+16+lr)
  const u16* qp = qbf + ((size_t)b*4096 + mbase + lr)*64 + gq*8;
  s16x8 qf[2][2];
  qf[0][0] = *(const s16x8*)qp;
  qf[0][1] = *(const s16x8*)(qp + 32);
  qf[1][0] = *(const s16x8*)(qp + 16*64);
  qf[1][1] = *(const s16x8*)(qp + 16*64 + 32);

  f32x4 acc[2][8];
  #pragma unroll
  for(int pf=0;pf<2;++pf)
    #pragma unroll
    for(int i=0;i<8;++i) acc[pf][i] = (f32x4)0.f;
  float mrun[2] = {-3.0e38f, -3.0e38f}, lrun[2] = {0.f, 0.f};

  const u16* kb0 = kbf + (size_t)b*4096*64 + (size_t)lr*64 + gq*8;
  const u16* vb0 = vbf + ((size_t)b*128 + lr)*4096 + gq*8;

  // wave-private P bounce: 4KB per wave (floats offset wid*1024)
  u16* pw = (u16*)(smem + wid*1024);
  u32 swz = ((u32)(lr & 7)) << 4;
  u32 wb[4];
  #pragma unroll
  for(int nf=0;nf<4;++nf) wb[nf] = ((u32)((lr*64 + nf*16 + gq*4)*2)) ^ swz;
  u32 rb0 = ((u32)((lr*64 + gq*8)*2)) ^ swz;
  u32 rb1 = ((u32)((lr*64 + 32 + gq*8)*2)) ^ swz;

  for(int t=0; t<8; ++t){
    int nt = wid*8 + t;
    const u16* kp = kb0 + (size_t)nt*64*64;
    f32x4 sf[2][4];
    __builtin_amdgcn_s_setprio(1);
    #pragma unroll
    for(int nf=0;nf<4;++nf){
      s16x8 ka0 = *(const s16x8*)(kp + nf*16*64);
      s16x8 ka1 = *(const s16x8*)(kp + nf*16*64 + 32);
      #pragma unroll
      for(int pf=0;pf<2;++pf){
        f32x4 z = (f32x4)0.f;
        z = __builtin_amdgcn_mfma_f32_16x16x32_bf16(ka0, qf[pf][0], z, 0, 0, 0);
        z = __builtin_amdgcn_mfma_f32_16x16x32_bf16(ka1, qf[pf][1], z, 0, 0, 0);
        sf[pf][nf] = z;
      }
    }
    __builtin_amdgcn_s_setprio(0);
    #pragma unroll
    for(int pf=0;pf<2;++pf){
      float tm = -3.0e38f;
      #pragma unroll
      for(int nf=0;nf<4;++nf)
        #pragma unroll
        for(int r=0;r<4;++r) tm = fmaxf(tm, sf[pf][nf][r]);
      tm = fmaxf(tm, __shfl_xor(tm, 16));
      tm = fmaxf(tm, __shfl_xor(tm, 32));
      float mnew = fmaxf(mrun[pf], tm);
      float alpha = __expf(mrun[pf] - mnew);
      float ps = 0.f;
      #pragma unroll
      for(int nf=0;nf<4;++nf)
        #pragma unroll
        for(int r=0;r<4;++r){ float p = __expf(sf[pf][nf][r] - mnew); sf[pf][nf][r] = p; ps += p; }
      ps += __shfl_xor(ps, 16);
      ps += __shfl_xor(ps, 32);
      lrun[pf] = lrun[pf]*alpha + ps;
      mrun[pf] = mnew;
      #pragma unroll
      for(int i=0;i<8;++i) acc[pf][i] *= alpha;
      #pragma unroll
      for(int nf=0;nf<4;++nf){
        u32 lo = (u32)f2b(sf[pf][nf][0]) | ((u32)f2b(sf[pf][nf][1]) << 16);
        u32 hi = (u32)f2b(sf[pf][nf][2]) | ((u32)f2b(sf[pf][nf][3]) << 16);
        uint2 wv; wv.x = lo; wv.y = hi;
        *(uint2*)((char*)pw + (pf*2048 + wb[nf])) = wv;
      }
    }
    s16x8 pb[2][2];
    #pragma unroll
    for(int pf=0;pf<2;++pf){
      pb[pf][0] = *(const s16x8*)((char*)pw + (pf*2048 + rb0));
      pb[pf][1] = *(const s16x8*)((char*)pw + (pf*2048 + rb1));
    }
    const u16* vp = vb0 + nt*64;
    __builtin_amdgcn_s_setprio(1);
    #pragma unroll
    for(int cf=0;cf<8;++cf){
      s16x8 va0 = *(const s16x8*)(vp + (size_t)cf*16*4096);
      s16x8 va1 = *(const s16x8*)(vp + (size_t)cf*16*4096 + 32);
      #pragma unroll
      for(int pf=0;pf<2;++pf){
        acc[pf][cf] = __builtin_amdgcn_mfma_f32_16x16x32_bf16(va0, pb[pf][0], acc[pf][cf], 0, 0, 0);
        acc[pf][cf] = __builtin_amdgcn_mfma_f32_16x16x32_bf16(va1, pb[pf][1], acc[pf][cf], 0, 0, 0);
      }
    }
    __builtin_amdgcn_s_setprio(0);
  }

  // stats dump: [wid][pf][lr]
  if(gq == 0){
    #pragma unroll
    for(int pf=0;pf<2;++pf){
      sst[((wid*2+pf)*16 + lr)*2 + 0] = mrun[pf];
      sst[((wid*2+pf)*16 + lr)*2 + 1] = lrun[pf];
    }
  }

  // two-phase combine: per pf, dump 64KB (8 waves x 8KB) then merge (cf = wid)
  #pragma unroll
  for(int pf=0;pf<2;++pf){
    __syncthreads();   // P-bounce use / previous-phase reads complete; stats visible
    #pragma unroll
    for(int cf=0;cf<8;++cf)
      *(f32x4*)(smem + wid*2048 + cf*256 + lane*4) = acc[pf][cf];
    __syncthreads();
    float mw[8], lw[8], Mx = -3.0e38f;
    #pragma unroll
    for(int w=0;w<8;++w){
      mw[w] = sst[((w*2+pf)*16 + lr)*2 + 0];
      lw[w] = sst[((w*2+pf)*16 + lr)*2 + 1];
      Mx = fmaxf(Mx, mw[w]);
    }
    float sw[8], lstar = 0.f;
    #pragma unroll
    for(int w=0;w<8;++w){ sw[w] = __expf(mw[w] - Mx); lstar += lw[w]*sw[w]; }
    float inv = 1.f/lstar;
    int m = mbase + pf*16 + lr;
    int cf = wid;
    f32x4 O = (f32x4)0.f;
    #pragma unroll
    for(int w=0;w<8;++w)
      O += sw[w] * *(const f32x4*)(smem + w*2048 + cf*256 + lane*4);
    int c0 = cf*16 + gq*4;
    size_t rbase = ((size_t)b*4096 + m)*128 + c0;
    s16x4 xr = *(const s16x4*)(x2b + rbase);
    s16x4 ir = *(const s16x4*)(idbb + rbase);
    #pragma unroll
    for(int r=0;r<4;++r){
      float val = O[r]*inv + b2f(xr[r]) + b2f(ir[r]);
      out[((size_t)b*128 + c0 + r)*4096 + m] = lrelu(val);
    }
  }
}

extern "C" void kernel_launch(void* const* d_in, const int* in_sizes, int n_in,
                              void* d_out, int out_size, void* d_ws, size_t ws_size,
                              hipStream_t stream) {
  const float* x    = (const float*)d_in[0];
  const float* W_up = (const float*)d_in[1];
  const float* b_up = (const float*)d_in[2];
  const float* g0   = (const float*)d_in[3];
  const float* be0  = (const float*)d_in[4];
  const float* m0   = (const float*)d_in[5];
  const float* v0   = (const float*)d_in[6];
  const float* W_r0 = (const float*)d_in[7];
  const float* g1   = (const float*)d_in[8];
  const float* be1  = (const float*)d_in[9];
  const float* m1   = (const float*)d_in[10];
  const float* v1   = (const float*)d_in[11];
  const float* W_r1 = (const float*)d_in[12];
  const float* g2   = (const float*)d_in[13];
  const float* be2  = (const float*)d_in[14];
  const float* m2   = (const float*)d_in[15];
  const float* v2   = (const float*)d_in[16];
  const float* Wq   = (const float*)d_in[17];
  const float* bq   = (const float*)d_in[18];
  const float* Wk   = (const float*)d_in[19];
  const float* bk   = (const float*)d_in[20];
  const float* Wv   = (const float*)d_in[21];
  const float* bv   = (const float*)d_in[22];

  float* ws = (float*)d_ws;
  u16* xh   = (u16*)(ws + 0);         // [4,1024,256]
  u16* ub   = (u16*)(ws + 524288);    // [4,4096,256]
  u16* idbb = (u16*)(ws + 2621440);   // [4,4096,128]
  u16* x1b  = (u16*)(ws + 3670016);   // [4,4096,128]
  u16* x2b  = (u16*)(ws + 4718592);   // [4,4096,128]
  u16* qbf  = (u16*)(ws + 5767168);   // [4,4096,64]
  u16* kbf  = (u16*)(ws + 6291456);   // [4,4096,64]
  u16* vbf  = (u16*)(ws + 6815744);   // [4,128,4096]
  u16* wtu  = (u16*)(ws + 7864320);   // [128,2304]
  u16* wtr0 = (u16*)(ws + 8011776);   // [128,1152]
  u16* wtr1 = (u16*)(ws + 8085504);   // [128,1152]
  u16* wqk  = (u16*)(ws + 8159232);   // [128,128]
  u16* wvb  = (u16*)(ws + 8167424);   // [128,128]
  float* out = (float*)d_out;

  // weight transforms
  k_wconv<256><<<1152, 256, 0, stream>>>(W_up, wtu);
  k_wconv<128><<<576, 256, 0, stream>>>(W_r0, wtr0);
  k_wconv<128><<<576, 256, 0, stream>>>(W_r1, wtr1);
  k_wproj<<<128, 256, 0, stream>>>(Wq, Wk, Wv, wqk, wvb);
  // input layout + upsample
  k_tr<<<1024, 256, 0, stream>>>(x, xh);
  k_up8<<<2048, 256, 0, stream>>>(xh, ub);
  // convs (MFMA implicit GEMM, round-4 config)
  k_cmfma<256><<<512, 128, 0, stream>>>(ub, wtu, b_up, g0, be0, m0, v0, idbb);
  k_cmfma<128><<<512, 128, 0, stream>>>(idbb, wtr0, nullptr, g1, be1, m1, v1, x1b);
  k_cmfma<128><<<512, 128, 0, stream>>>(x1b, wtr1, nullptr, g2, be2, m2, v2, x2b);
  // projections
  k_projqk<<<512, 128, 0, stream>>>(x2b, wqk, bq, bk, qbf, kbf);
  k_projv<<<512, 128, 0, stream>>>(x2b, wvb, bv, vbf);
  // attention + residuals + lrelu (KV-split x8, 8 waves/block)
  k_fattn2<<<512, 512, 0, stream>>>(qbf, kbf, vbf, x2b, idbb, out);
}